// Round 3
// baseline (307.009 us; speedup 1.0000x reference)
//
#include <hip/hip_runtime.h>
#include <math.h>

#define NB 10
#define H 512
#define W 512
#define OH 507
#define OW 507
#define TW 32           // output tile width
#define TH 16           // output tile height
#define HC (TW + 7)     // 39 hist cols  (ox0-1 .. ox0+TW+6)
#define HR (TH + 7)     // 23 hist rows
#define IC (TW + 9)     // 41 input cols (ox0-2 .. ox0+TW+7)
#define IR (TH + 9)     // 25 input rows

// numpy float32 remainder (np.mod): fmod then sign-fix, each op exact IEEE f32.
__device__ __forceinline__ float f32mod10(float a) {
    float r = fmodf(a, 10.0f);               // exact by definition
    if (r < 0.0f) r = __fadd_rn(r, 10.0f);   // -0.0 stays (matches np: r!=0 test)
    return r;
}

__global__ __launch_bounds__(256, 2)
void hog_fused(const float* __restrict__ x, float* __restrict__ out) {
    __shared__ float xin[IR][IC];            // 25*41  = 1025 f
    __shared__ float hist[NB][HR][HC];       // 10*23*39 = 8970 f
    __shared__ float colsum[NB][TH][HC];     // 10*16*39 = 6240 f

    const int tid = threadIdx.x;
    const int ox0 = blockIdx.x * TW;
    const int oy0 = blockIdx.y * TH;
    const int n   = blockIdx.z;
    const float* __restrict__ xp = x + (size_t)n * (H * W);

    // ---- zero hist ----
    float* hflat = &hist[0][0][0];
    for (int i = tid; i < NB * HR * HC; i += 256) hflat[i] = 0.0f;

    // ---- load input tile with halo (zero padded outside image) ----
    float* xflat = &xin[0][0];
    for (int i = tid; i < IR * IC; i += 256) {
        int r = i / IC, c = i % IC;
        int gy = oy0 - 2 + r, gx = ox0 - 2 + c;
        float v = 0.0f;
        if (gy >= 0 && gy < H && gx >= 0 && gx < W) v = xp[gy * W + gx];
        xflat[i] = v;
    }
    __syncthreads();

    // ---- Sobel + phase + 2-bin scatter into LDS hist ----
    // All math is bit-exact IEEE f32 in numpy tap-loop order (no FMA
    // contraction), phase = correctly-rounded f32 atan2 via double.
    for (int p = tid; p < HR * HC; p += 256) {
        int hr = p / HC, hc = p % HC;
        int hy = oy0 - 1 + hr, hx = ox0 - 1 + hc;
        if (hy < 0 || hy >= H || hx < 0 || hx >= W) continue;  // pool pad: zero
        float a00 = xin[hr][hc],     a01 = xin[hr][hc + 1],     a02 = xin[hr][hc + 2];
        float a10 = xin[hr + 1][hc],                            a12 = xin[hr + 1][hc + 2];
        float a20 = xin[hr + 2][hc], a21 = xin[hr + 2][hc + 1], a22 = xin[hr + 2][hc + 2];

        // gx: taps row-major: +1*a00, -1*a02, +2*a10, -2*a12, +1*a20, -1*a22
        float gxv = __fadd_rn(a00, -a02);
        gxv = __fadd_rn(gxv, __fmul_rn(2.0f, a10));
        gxv = __fadd_rn(gxv, -__fmul_rn(2.0f, a12));
        gxv = __fadd_rn(gxv, a20);
        gxv = __fadd_rn(gxv, -a22);
        // gy (mat.T): +1*a00, +2*a01, +1*a02, -1*a20, -2*a21, -1*a22
        float gyv = __fadd_rn(a00, __fmul_rn(2.0f, a01));
        gyv = __fadd_rn(gyv, a02);
        gyv = __fadd_rn(gyv, -a20);
        gyv = __fadd_rn(gyv, -__fmul_rn(2.0f, a21));
        gyv = __fadd_rn(gyv, -a22);

        float nrm = __fsqrt_rn(__fadd_rn(__fmul_rn(gxv, gxv), __fmul_rn(gyv, gyv)));
        // numpy f32 arctan2 is correctly rounded -> simulate via f64 + cast
        float phf = (float)atan2((double)gxv, (double)gyv);
        // phase / f32(pi) * 10, each op rounded f32
        float pintf = __fmul_rn(__fdiv_rn(phf, (float)3.14159265358979323846), 10.0f);

        float bfv = floorf(pintf), tfv = ceilf(pintf);             // exact
        float fm = f32mod10(pintf), bm = f32mod10(bfv), tm = f32mod10(tfv);
        float t_v = __fmul_rn(nrm, __fsub_rn(1.0f, __fsub_rn(tm, fm)));
        float b_v = __fmul_rn(nrm, __fsub_rn(1.0f, __fsub_rn(fm, bm)));
        int ib = (((int)bfv % NB) + NB) % NB;   // python int %: sign of divisor
        int it = (((int)tfv % NB) + NB) % NB;

        // one thread owns this pixel; add b first then t (matches set+add)
        hist[ib][hr][hc] = __fadd_rn(hist[ib][hr][hc], b_v);
        hist[it][hr][hc] = __fadd_rn(hist[it][hr][hc], t_v);
    }
    __syncthreads();

    // ---- vertical 8-row sliding sum ----
    for (int q = tid; q < NB * HC; q += 256) {
        int b = q / HC, hc = q % HC;
        float s = 0.0f;
        #pragma unroll
        for (int hr = 0; hr < 8; ++hr) s += hist[b][hr][hc];
        colsum[b][0][hc] = s;
        for (int i = 1; i < TH; ++i) {
            s += hist[b][i + 7][hc] - hist[b][i - 1][hc];
            colsum[b][i][hc] = s;
        }
    }
    __syncthreads();

    // ---- horizontal 8-col sum + coalesced store ----
    const int tx = tid & 31;
    const int ty = tid >> 5;
    const int ox = ox0 + tx;
    for (int b = 0; b < NB; ++b) {
        #pragma unroll
        for (int g = 0; g < TH / 8; ++g) {
            int i  = g * 8 + ty;
            int oy = oy0 + i;
            if (ox < OW && oy < OH) {
                float s = 0.0f;
                #pragma unroll
                for (int k = 0; k < 8; ++k) s += colsum[b][i][tx + k];
                out[((size_t)(n * NB + b) * OH + oy) * OW + ox] = s * (1.0f / 64.0f);
            }
        }
    }
}

extern "C" void kernel_launch(void* const* d_in, const int* in_sizes, int n_in,
                              void* d_out, int out_size, void* d_ws, size_t ws_size,
                              hipStream_t stream) {
    const float* x = (const float*)d_in[0];
    // d_in[1] is the fixed Sobel weight [2,1,3,3]; hard-coded in the kernel.
    float* out = (float*)d_out;
    dim3 grid((OW + TW - 1) / TW, (OH + TH - 1) / TH, 32);
    hog_fused<<<grid, dim3(256), 0, stream>>>(x, out);
}

// Round 4
// 218.445 us; speedup vs baseline: 1.4054x; 1.4054x over previous
//
#include <hip/hip_runtime.h>
#include <math.h>

#define NB 10
#define H 512
#define W 512
#define OH 507
#define OW 507
#define TW 32           // output tile width
#define TH 16           // output tile height
#define HC (TW + 7)     // 39 hist cols  (ox0-1 .. ox0+TW+6)
#define HR (TH + 7)     // 23 hist rows
#define IC (TW + 9)     // 41 input cols (ox0-2 .. ox0+TW+7)
#define IR (TH + 9)     // 25 input rows

// numpy float32 remainder (np.mod): fmod then sign-fix, each op exact IEEE f32.
__device__ __forceinline__ float f32mod10(float a) {
    float r = fmodf(a, 10.0f);
    if (r < 0.0f) r = __fadd_rn(r, 10.0f);
    return r;
}

__global__ __launch_bounds__(256, 4)
void hog_fused(const float* __restrict__ x, float* __restrict__ out) {
    __shared__ __align__(16) float xin[IR][IC];      // 1025 f; reused as buf0 later
    __shared__ __align__(16) float hist[NB][HR][HC]; // 8970 f
    // total 9995 f = 39,980 B -> 4 blocks/CU

    const int tid = threadIdx.x;
    const int ox0 = blockIdx.x * TW;
    const int oy0 = blockIdx.y * TH;
    const int n   = blockIdx.z;
    const float* __restrict__ xp = x + (size_t)n * (H * W);

    // ---- zero hist (vectorized) ----
    float* hflat = &hist[0][0][0];
    {
        float4* h4 = (float4*)hflat;                 // 8970 = 2242*4 + 2
        for (int i = tid; i < 2242; i += 256) h4[i] = make_float4(0.f, 0.f, 0.f, 0.f);
        if (tid < 2) hflat[8968 + tid] = 0.0f;
    }

    // ---- load input tile with halo (zero padded outside image) ----
    float* xflat = &xin[0][0];
    for (int i = tid; i < IR * IC; i += 256) {
        int r = i / IC, c = i % IC;
        int gy = oy0 - 2 + r, gx = ox0 - 2 + c;
        float v = 0.0f;
        if (gy >= 0 && gy < H && gx >= 0 && gx < W) v = xp[gy * W + gx];
        xflat[i] = v;
    }
    __syncthreads();

    // ---- Sobel + phase + 2-bin scatter into LDS hist ----
    for (int p = tid; p < HR * HC; p += 256) {
        int hr = p / HC, hc = p % HC;
        int hy = oy0 - 1 + hr, hx = ox0 - 1 + hc;
        if (hy < 0 || hy >= H || hx < 0 || hx >= W) continue;  // pool pad: zero
        float a00 = xin[hr][hc],     a01 = xin[hr][hc + 1],     a02 = xin[hr][hc + 2];
        float a10 = xin[hr + 1][hc],                            a12 = xin[hr + 1][hc + 2];
        float a20 = xin[hr + 2][hc], a21 = xin[hr + 2][hc + 1], a22 = xin[hr + 2][hc + 2];

        // exact numpy-order f32 conv (no contraction) — proven in round 3
        float gxv = __fadd_rn(a00, -a02);
        gxv = __fadd_rn(gxv, __fmul_rn(2.0f, a10));
        gxv = __fadd_rn(gxv, -__fmul_rn(2.0f, a12));
        gxv = __fadd_rn(gxv, a20);
        gxv = __fadd_rn(gxv, -a22);
        float gyv = __fadd_rn(a00, __fmul_rn(2.0f, a01));
        gyv = __fadd_rn(gyv, a02);
        gyv = __fadd_rn(gyv, -a20);
        gyv = __fadd_rn(gyv, -__fmul_rn(2.0f, a21));
        gyv = __fadd_rn(gyv, -a22);

        float nrm = __fsqrt_rn(__fadd_rn(__fmul_rn(gxv, gxv), __fmul_rn(gyv, gyv)));

        // ---- fast f32 atan2(gxv, gyv) ----
        float ay_ = fabsf(gxv), ax_ = fabsf(gyv);
        float hi = fmaxf(ax_, ay_), lo = fminf(ax_, ay_);
        if (hi == 0.0f) continue;            // gx=gy=0: nrm=0, contributes 0
        bool exact = (hi < 1e-30f);          // denormal-ratio hazard -> exact path
        float pint;
        if (!exact) {
            float t  = lo / hi;              // [0,1]
            bool red = t > 0.41421356f;
            float u  = red ? (t - 1.0f) / (t + 1.0f) : t;
            float z  = u * u;
            float pl = ((8.05374449538e-2f * z - 1.38776856032e-1f) * z
                        + 1.99777106478e-1f) * z - 3.33329491539e-1f;
            float a  = u + u * z * pl;                 // atan(u)
            if (red) a += 0.7853981634f;               // atan(t)
            if (ay_ > ax_) a = 1.5707963268f - a;      // undo swap
            if (gyv < 0.0f) a = 3.1415926536f - a;     // x<0 quadrant
            float ph = (gxv < 0.0f) ? -a : a;
            pint = ph * 3.1830988618f;                 // *10/pi
            // near any bin boundary / wrap: decisions could flip -> exact path
            if (fabsf(pint - rintf(pint)) < 1e-3f) exact = true;
        }

        float b_v, t_v;
        int ib, it;
        if (exact) {
            // bit-exact round-3 chain (matches np f32 reference)
            float phf = (float)atan2((double)gxv, (double)gyv);
            float pe  = __fmul_rn(__fdiv_rn(phf, (float)3.14159265358979323846), 10.0f);
            float bfv = floorf(pe), tfv = ceilf(pe);
            float fm = f32mod10(pe), bm = f32mod10(bfv), tm = f32mod10(tfv);
            t_v = __fmul_rn(nrm, __fsub_rn(1.0f, __fsub_rn(tm, fm)));
            b_v = __fmul_rn(nrm, __fsub_rn(1.0f, __fsub_rn(fm, bm)));
            ib = (((int)bfv % NB) + NB) % NB;
            it = (((int)tfv % NB) + NB) % NB;
        } else {
            // pint strictly inside (-10,10), >=1e-3 from any integer
            float bfv = floorf(pint), tfv = ceilf(pint);
            float fm = (pint < 0.0f) ? pint + 10.0f : pint;
            float bm = (bfv  < 0.0f) ? bfv  + 10.0f : bfv;
            float tm = (tfv == 10.0f) ? 0.0f : ((tfv < 0.0f) ? tfv + 10.0f : tfv);
            t_v = nrm * (1.0f - (tm - fm));
            b_v = nrm * (1.0f - (fm - bm));
            int bi = (int)bfv, ti = (int)tfv;          // [-10,9], [-9,10]
            ib = (bi < 0) ? bi + 10 : bi;
            it = (ti < 0) ? ti + 10 : ((ti == 10) ? 0 : ti);
        }
        hist[ib][hr][hc] = __fadd_rn(hist[ib][hr][hc], b_v);
        hist[it][hr][hc] = __fadd_rn(hist[it][hr][hc], t_v);
    }
    __syncthreads();

    // ---- vertical 8-row sliding sum, IN PLACE ----
    // colsum(i) = sum_{hr=i..i+7} hist rows; store colsum(0) in dead xin,
    // colsum(i>=1) into hist row i-1 (dead after window i reads it).
    float* buf0 = &xin[0][0];                          // [NB][HC] = 390 f
    for (int q = tid; q < NB * HC; q += 256) {
        int b = q / HC, hc = q % HC;
        float s = 0.0f;
        #pragma unroll
        for (int hr = 0; hr < 8; ++hr) s += hist[b][hr][hc];
        buf0[b * HC + hc] = s;
        #pragma unroll 4
        for (int i = 1; i < TH; ++i) {
            s += hist[b][i + 7][hc] - hist[b][i - 1][hc];
            hist[b][i - 1][hc] = s;                    // overwrite after last read
        }
    }
    __syncthreads();

    // ---- horizontal 8-col sum + coalesced store ----
    const int tx = tid & 31;
    const int ty = tid >> 5;
    const int ox = ox0 + tx;
    for (int b = 0; b < NB; ++b) {
        #pragma unroll
        for (int g = 0; g < TH / 8; ++g) {
            int i  = g * 8 + ty;
            int oy = oy0 + i;
            if (ox < OW && oy < OH) {
                const float* cs = (i == 0) ? &buf0[b * HC] : &hist[b][i - 1][0];
                float s = 0.0f;
                #pragma unroll
                for (int k = 0; k < 8; ++k) s += cs[tx + k];
                out[((size_t)(n * NB + b) * OH + oy) * OW + ox] = s * (1.0f / 64.0f);
            }
        }
    }
}

extern "C" void kernel_launch(void* const* d_in, const int* in_sizes, int n_in,
                              void* d_out, int out_size, void* d_ws, size_t ws_size,
                              hipStream_t stream) {
    const float* x = (const float*)d_in[0];
    // d_in[1] is the fixed Sobel weight [2,1,3,3]; hard-coded in the kernel.
    float* out = (float*)d_out;
    dim3 grid((OW + TW - 1) / TW, (OH + TH - 1) / TH, 32);
    hog_fused<<<grid, dim3(256), 0, stream>>>(x, out);
}

// Round 6
// 216.653 us; speedup vs baseline: 1.4171x; 1.0083x over previous
//
#include <hip/hip_runtime.h>
#include <math.h>

#define NB 10
#define H 512
#define W 512
#define OH 507
#define OW 507
#define TW 32           // output tile width
#define TH 16           // output tile height
#define HC (TW + 7)     // 39 hist cols  (ox0-1 .. ox0+TW+6)
#define HR (TH + 7)     // 23 hist rows
#define IC (TW + 9)     // 41 input cols (ox0-2 .. ox0+TW+7)
#define IR (TH + 9)     // 25 input rows

// numpy float32 remainder (np.mod): fmod then sign-fix, each op exact IEEE f32.
__device__ __forceinline__ float f32mod10(float a) {
    float r = fmodf(a, 10.0f);
    if (r < 0.0f) r = __fadd_rn(r, 10.0f);
    return r;
}

__global__ __launch_bounds__(256, 4)
void hog_fused(const float* __restrict__ x, float* __restrict__ out) {
    __shared__ __align__(16) float xin[IR][IC];      // 1025 f; reused as buf0 later
    __shared__ __align__(16) float hist[NB][HR][HC]; // 8970 f
    // total 9995 f = 39,980 B -> 4 blocks/CU

    const int tid = threadIdx.x;
    const int ox0 = blockIdx.x * TW;
    const int oy0 = blockIdx.y * TH;
    const int n   = blockIdx.z;
    const float* __restrict__ xp = x + (size_t)n * (H * W);

    // ---- zero hist (vectorized) ----
    float* hflat = &hist[0][0][0];
    {
        float4* h4 = (float4*)hflat;                 // 8970 = 2242*4 + 2
        for (int i = tid; i < 2242; i += 256) h4[i] = make_float4(0.f, 0.f, 0.f, 0.f);
        if (tid < 2) hflat[8968 + tid] = 0.0f;
    }

    // ---- load input tile with halo (zero padded outside image) ----
    float* xflat = &xin[0][0];
    for (int i = tid; i < IR * IC; i += 256) {
        int r = i / IC, c = i % IC;
        int gy = oy0 - 2 + r, gx = ox0 - 2 + c;
        float v = 0.0f;
        if (gy >= 0 && gy < H && gx >= 0 && gx < W) v = xp[gy * W + gx];
        xflat[i] = v;
    }
    __syncthreads();

    // ---- Sobel + phase + 2-bin scatter into LDS hist ----
    for (int p = tid; p < HR * HC; p += 256) {
        int hr = p / HC, hc = p % HC;
        int hy = oy0 - 1 + hr, hx = ox0 - 1 + hc;
        if (hy < 0 || hy >= H || hx < 0 || hx >= W) continue;  // pool pad: zero
        float a00 = xin[hr][hc],     a01 = xin[hr][hc + 1],     a02 = xin[hr][hc + 2];
        float a10 = xin[hr + 1][hc],                            a12 = xin[hr + 1][hc + 2];
        float a20 = xin[hr + 2][hc], a21 = xin[hr + 2][hc + 1], a22 = xin[hr + 2][hc + 2];

        // exact numpy-order f32 conv (no contraction) — proven in round 3
        float gxv = __fadd_rn(a00, -a02);
        gxv = __fadd_rn(gxv, __fmul_rn(2.0f, a10));
        gxv = __fadd_rn(gxv, -__fmul_rn(2.0f, a12));
        gxv = __fadd_rn(gxv, a20);
        gxv = __fadd_rn(gxv, -a22);
        float gyv = __fadd_rn(a00, __fmul_rn(2.0f, a01));
        gyv = __fadd_rn(gyv, a02);
        gyv = __fadd_rn(gyv, -a20);
        gyv = __fadd_rn(gyv, -__fmul_rn(2.0f, a21));
        gyv = __fadd_rn(gyv, -a22);

        float ay_ = fabsf(gxv), ax_ = fabsf(gyv);
        float hi = fmaxf(ax_, ay_), lo = fminf(ax_, ay_);
        if (hi == 0.0f) continue;            // atan2(0,0)=0 -> contributes 0
        float nrm = __builtin_amdgcn_sqrtf(
            __fadd_rn(__fmul_rn(gxv, gxv), __fmul_rn(gyv, gyv)));

        // ---- fast f32 atan2(gxv, gyv) * 10/pi, divide-free ----
        bool exact = (hi < 1e-30f) || (hi > 1e30f);   // rcp denormal hazards
        float pint = 0.0f;
        if (!exact) {
            float t  = lo * __builtin_amdgcn_rcpf(hi);            // [0,1]
            bool red = t > 0.41421356f;
            float u  = red ? (t - 1.0f) * __builtin_amdgcn_rcpf(t + 1.0f) : t;
            float z  = u * u;
            float pl = ((8.05374449538e-2f * z - 1.38776856032e-1f) * z
                        + 1.99777106478e-1f) * z - 3.33329491539e-1f;
            float a  = fmaf(u * z, pl, u);             // atan(u)
            if (red) a += 0.78539816339744831f;
            if (ay_ > ax_) a = 1.57079632679489662f - a;
            if (gyv < 0.0f) a = 3.14159265358979324f - a;
            float ph = (gxv < 0.0f) ? -a : a;
            pint = ph * 3.18309886183790672f;          // *10/pi
            // near any bin boundary / wrap: decision could differ -> exact path
            if (fabsf(pint - rintf(pint)) < 1e-4f) exact = true;
        }

        float b_v, t_v;
        int ib, it;
        if (exact) {
            // bit-exact round-3 chain (matches np f32 reference)
            float phf = (float)atan2((double)gxv, (double)gyv);
            float pe  = __fmul_rn(__fdiv_rn(phf, (float)3.14159265358979323846), 10.0f);
            float bfv = floorf(pe), tfv = ceilf(pe);
            float fm = f32mod10(pe), bm = f32mod10(bfv), tm = f32mod10(tfv);
            t_v = __fmul_rn(nrm, __fsub_rn(1.0f, __fsub_rn(tm, fm)));
            b_v = __fmul_rn(nrm, __fsub_rn(1.0f, __fsub_rn(fm, bm)));
            ib = (((int)bfv % NB) + NB) % NB;
            it = (((int)tfv % NB) + NB) % NB;
        } else {
            // pint in (-10,10), >=1e-4 from any integer (so ceil = floor+1).
            // Wrap strips (t-index 0, tm=0) occur exactly when ib==9:
            //   bfv==9  (pint in ( 9,10)): t_v = nrm*(1+f),  f = pint
            //   bfv==-1 (pint in (-1, 0)): t_v = nrm*(1+f),  f = pint+10
            float bfv  = floorf(pint);
            float frac = pint - bfv;
            float fm   = (pint < 0.0f) ? pint + 10.0f : pint;  // f32 mod
            b_v = nrm * (1.0f - frac);
            int bi = (int)bfv;                         // [-10,9]
            ib = (bi < 0) ? bi + 10 : bi;
            if (ib == 9) { it = 0;      t_v = nrm * (1.0f + fm); }
            else         { it = ib + 1; t_v = nrm * frac; }
        }
        hist[ib][hr][hc] = __fadd_rn(hist[ib][hr][hc], b_v);
        hist[it][hr][hc] = __fadd_rn(hist[it][hr][hc], t_v);
    }
    __syncthreads();

    // ---- vertical 8-row sliding sum, IN PLACE ----
    float* buf0 = &xin[0][0];                          // [NB][HC] = 390 f
    for (int q = tid; q < NB * HC; q += 256) {
        int b = q / HC, hc = q % HC;
        float s = 0.0f;
        #pragma unroll
        for (int hr = 0; hr < 8; ++hr) s += hist[b][hr][hc];
        buf0[b * HC + hc] = s;
        #pragma unroll 4
        for (int i = 1; i < TH; ++i) {
            s += hist[b][i + 7][hc] - hist[b][i - 1][hc];
            hist[b][i - 1][hc] = s;                    // overwrite after last read
        }
    }
    __syncthreads();

    // ---- horizontal 8-col sum + coalesced store ----
    const int tx = tid & 31;
    const int ty = tid >> 5;
    const int ox = ox0 + tx;
    for (int b = 0; b < NB; ++b) {
        #pragma unroll
        for (int g = 0; g < TH / 8; ++g) {
            int i  = g * 8 + ty;
            int oy = oy0 + i;
            if (ox < OW && oy < OH) {
                const float* cs = (i == 0) ? &buf0[b * HC] : &hist[b][i - 1][0];
                float s = 0.0f;
                #pragma unroll
                for (int k = 0; k < 8; ++k) s += cs[tx + k];
                out[((size_t)(n * NB + b) * OH + oy) * OW + ox] = s * (1.0f / 64.0f);
            }
        }
    }
}

extern "C" void kernel_launch(void* const* d_in, const int* in_sizes, int n_in,
                              void* d_out, int out_size, void* d_ws, size_t ws_size,
                              hipStream_t stream) {
    const float* x = (const float*)d_in[0];
    // d_in[1] is the fixed Sobel weight [2,1,3,3]; hard-coded in the kernel.
    float* out = (float*)d_out;
    dim3 grid((OW + TW - 1) / TW, (OH + TH - 1) / TH, 32);
    hog_fused<<<grid, dim3(256), 0, stream>>>(x, out);
}